// Round 4
// baseline (313.820 us; speedup 1.0000x reference)
//
#include <hip/hip_runtime.h>

// Problem: 500 GD steps on a 2-conv model, loss = ||FFT(y)-FFT(yhat)||^2.
// Parseval => loss = 256 * sum (y - yhat)^2 ; mean over batch 1024 => 2c = 0.5.
// yhat[n,w] = beff + sum_{i=(r,a)} A[i] * xpad[n, r, w+a-10],
//   A[r,a] = sum_h k2[h]*k1[r-h+1,a],  beff = b2 + b1*(k2[0]+k2[1]+k2[2]).
// Sufficient stats: XX[63][63], XY[63], Sx[63], Ysum. Train on those; then apply.
//
// k_train R4: R3 structure (readlane matvec, DPP sums, replicated shifted k1)
// + __launch_bounds__(64,1) and asm keep-alive pins on XXr so the 64-element
// augmented-matrix row actually LIVES IN VGPRS across the 500-iter loop.
// R3's rocprof showed FETCH_SIZE=13.4MB/dispatch (ST is 16KB): the allocator,
// capped at 68 VGPRs by the default occupancy target, was re-loading the
// matrix from L2 every iteration. That VMEM latency was the critical path.
// k_stats R4: column tile j = 16*q + tj (was 4*tj + p) so the 16 lanes of a
// row read consecutive LDS words -> no 8-way bank conflict on the vb loads.

#define NB1 4              // batch rows per k_stats block
#define NBLK 256           // 1024 / NB1
#define PSTRIDE 4096       // 3969 XX + 63 XY + 63 Sx + 1 Ysum = 4096
#define ST_OFF (NBLK * PSTRIDE)     // 1048576 floats
#define AF_OFF (ST_OFF + PSTRIDE)   // 1052672 floats

// ---------------- stats kernel ----------------
template <int ATOMIC>
__global__ __launch_bounds__(256) void k_stats(const float* __restrict__ in,
                                               float* __restrict__ Pbase) {
    __shared__ float xs[NB1][3][276];   // zero-padded rows: u+10, u in [-10,265]
    __shared__ float ys[NB1][256];
    const int tid = threadIdx.x;
    const int n0 = blockIdx.x * NB1;

    float* xsf = &xs[0][0][0];
    for (int p = tid; p < NB1 * 3 * 276; p += 256) xsf[p] = 0.f;
    __syncthreads();
    for (int p = tid; p < NB1 * 4 * 256; p += 256) {
        int w = p & 255, h = (p >> 8) & 3, n = p >> 10;
        float v = in[((n0 + n) * 4 + h) * 256 + w];
        if (h == 0) ys[n][w] = v;
        else xs[n][h - 1][10 + w] = v;
    }
    __syncthreads();

    // rows: i = 4*ti + p (broadcast across the 16 lanes of a row);
    // cols: j = 16*q + tj  -> lanes read CONSECUTIVE words (bank-conflict-free)
    const int ti = tid >> 4, tj = tid & 15;
    const int i0 = ti * 4;
    int ir[4], ia[4], jr[4], ja[4];
#pragma unroll
    for (int p = 0; p < 4; ++p) {
        int i = i0 + p; if (i > 62) i = 62;
        ir[p] = i / 21; ia[p] = i % 21;
        int j = p * 16 + tj; if (j > 62) j = 62;
        jr[p] = j / 21; ja[p] = j % 21;
    }
    float acc[4][4] = {{0.f, 0.f, 0.f, 0.f}, {0.f, 0.f, 0.f, 0.f},
                       {0.f, 0.f, 0.f, 0.f}, {0.f, 0.f, 0.f, 0.f}};
    for (int n = 0; n < NB1; ++n) {
        const float* ba0 = &xs[n][ir[0]][ia[0]];
        const float* ba1 = &xs[n][ir[1]][ia[1]];
        const float* ba2 = &xs[n][ir[2]][ia[2]];
        const float* ba3 = &xs[n][ir[3]][ia[3]];
        const float* bb0 = &xs[n][jr[0]][ja[0]];
        const float* bb1 = &xs[n][jr[1]][ja[1]];
        const float* bb2 = &xs[n][jr[2]][ja[2]];
        const float* bb3 = &xs[n][jr[3]][ja[3]];
#pragma unroll 4
        for (int w = 0; w < 256; ++w) {
            float va0 = ba0[w], va1 = ba1[w], va2 = ba2[w], va3 = ba3[w];
            float vb0 = bb0[w], vb1 = bb1[w], vb2 = bb2[w], vb3 = bb3[w];
            acc[0][0] += va0 * vb0; acc[0][1] += va0 * vb1;
            acc[0][2] += va0 * vb2; acc[0][3] += va0 * vb3;
            acc[1][0] += va1 * vb0; acc[1][1] += va1 * vb1;
            acc[1][2] += va1 * vb2; acc[1][3] += va1 * vb3;
            acc[2][0] += va2 * vb0; acc[2][1] += va2 * vb1;
            acc[2][2] += va2 * vb2; acc[2][3] += va2 * vb3;
            acc[3][0] += va3 * vb0; acc[3][1] += va3 * vb1;
            acc[3][2] += va3 * vb2; acc[3][3] += va3 * vb3;
        }
    }
    float* Pb = ATOMIC ? Pbase : (Pbase + blockIdx.x * PSTRIDE);
#pragma unroll
    for (int p = 0; p < 4; ++p)
#pragma unroll
        for (int q = 0; q < 4; ++q) {
            int i = i0 + p, j = q * 16 + tj;   // raw (unclamped) indices
            if (i < 63 && j < 63) {
                if (ATOMIC) unsafeAtomicAdd(&Pb[i * 63 + j], acc[p][q]);
                else Pb[i * 63 + j] = acc[p][q];
            }
        }
    if (tid < 127) {
        float a2 = 0.f;
        int slot;
        if (tid < 63) {
            int r = tid / 21, a = tid % 21;
            for (int n = 0; n < NB1; ++n) {
                const float* xa = &xs[n][r][a];
                const float* yy = ys[n];
                float s = 0.f;
                for (int w = 0; w < 256; ++w) s += xa[w] * yy[w];
                a2 += s;
            }
            slot = 3969 + tid;
        } else if (tid < 126) {
            int e = tid - 63, r = e / 21, a = e % 21;
            for (int n = 0; n < NB1; ++n) {
                const float* xa = &xs[n][r][a];
                float s = 0.f;
                for (int w = 0; w < 256; ++w) s += xa[w];
                a2 += s;
            }
            slot = 4032 + e;
        } else {
            for (int n = 0; n < NB1; ++n) {
                const float* yy = ys[n];
                float s = 0.f;
                for (int w = 0; w < 256; ++w) s += yy[w];
                a2 += s;
            }
            slot = 4095;
        }
        if (ATOMIC) unsafeAtomicAdd(&Pb[slot], a2);
        else Pb[slot] = a2;
    }
}

// ---------------- deterministic reduction over block partials ----------------
__global__ __launch_bounds__(256) void k_reduce(const float* __restrict__ P,
                                                float* __restrict__ ST) {
    int e = blockIdx.x * 256 + threadIdx.x;  // 0..4095, coalesced over b-iters
    double s = 0.0;
    for (int b = 0; b < NBLK; ++b) s += (double)P[b * PSTRIDE + e];
    ST[e] = (float)s;
}

// ---------------- DPP helpers (VALU-pipe cross-lane) ----------------
template <int CTRL>
__device__ __forceinline__ float dpp_sum_step(float v) {
    int moved = __builtin_amdgcn_update_dpp(0, __float_as_int(v), CTRL, 0xf, 0xf, false);
    return v + __int_as_float(moved);
}
// full-wave (64) sum; returns total as a wave-uniform value (via lane 63)
__device__ __forceinline__ float wave_sum64(float v) {
    v = dpp_sum_step<0x111>(v);   // row_shr:1
    v = dpp_sum_step<0x112>(v);   // row_shr:2
    v = dpp_sum_step<0x114>(v);   // row_shr:4
    v = dpp_sum_step<0x118>(v);   // row_shr:8
    v = dpp_sum_step<0x142>(v);   // row_bcast:15
    v = dpp_sum_step<0x143>(v);   // row_bcast:31
    return __int_as_float(__builtin_amdgcn_readlane(__float_as_int(v), 63));
}
__device__ __forceinline__ float lane_bcast(float v, int lane) {
    return __int_as_float(__builtin_amdgcn_readlane(__float_as_int(v), lane));
}

// ---------------- training: 500 GD steps, one wave, register-resident ------
// __launch_bounds__(64, 1): single wave per SIMD target -> full VGPR budget,
// so the 64-float augmented matrix row stays in registers (no per-iter VMEM).
__global__ __launch_bounds__(64, 1) void k_train(const float* __restrict__ ST,
                                                 const float* __restrict__ k1_in,
                                                 const float* __restrict__ b1_in,
                                                 const float* __restrict__ k2_in,
                                                 const float* __restrict__ b2_in,
                                                 float* __restrict__ AF) {
    const int t = threadIdx.x;

    // Augmented row M[t][:]: t<63 -> [XX[t,:], Sx[t]]; t==63 -> [Sx[:], NW].
    float XXr[64];
    if (t < 63) {
#pragma unroll
        for (int j = 0; j < 63; ++j) XXr[j] = ST[t * 63 + j];
        XXr[63] = ST[4032 + t];            // Sx[t]
    } else {
#pragma unroll
        for (int j = 0; j < 63; ++j) XXr[j] = ST[4032 + j];  // Sx[j]
        XXr[63] = 262144.f;                // NW = 1024*256
    }
    float XYr = (t < 63) ? ST[3969 + t] : ST[4095];    // XY[t] | Ysum

    // Pin the matrix row (and rhs) into VGPRs: prevents the register
    // allocator from sinking/rematerializing these loads inside the loop
    // (R3 counter evidence: FETCH_SIZE 13.4MB/dispatch vs 16KB input).
#pragma unroll
    for (int j = 0; j < 64; ++j) asm volatile("" : "+v"(XXr[j]));
    asm volatile("" : "+v"(XYr));

    // validity masks for the replicated/shifted k1 state
    const bool m_own = (t < 63);             // lane owns k1[t]
    const bool mu    = (t < 42);             // k1[t+21] exists
    const bool md    = (t >= 21 && t < 63);  // k1[t-21] exists (lane63 excluded)
    const bool mpp   = (t < 21);             // G[t+42] valid row for k1u update
    const bool mmm   = (t >= 42);            // G[t-42] valid row for k1d update

    // replicated state: k1v = k1[t], k1u = k1[t+21], k1d = k1[t-21] (masked 0)
    float k1v = m_own ? k1_in[t] : 0.f;
    float k1u = mu ? k1_in[t + 21] : 0.f;
    float k1d = md ? k1_in[t - 21] : 0.f;
    // scalars replicated in every lane (identical updates -> identical values)
    float k20 = k2_in[0], k21 = k2_in[1], k22 = k2_in[2];
    float b1 = b1_in[0], b2 = b2_in[0];

    const float LRf = 1e-7f;

    for (int it = 0; it < 500; ++it) {
        float S = k20 + k21 + k22;
        float beff = b2 + b1 * S;
        // A[t] = k20*k1[t+21] + k21*k1[t] + k22*k1[t-21]  (pure per-lane FMA)
        float A = k20 * k1u + k21 * k1v + k22 * k1d;
        float z = m_own ? A : beff;   // A==0 at lane 63

        // G_all = 0.5*(M.z - rhs) via readlane-broadcast matvec (no LDS)
        float a0 = 0.f, a1 = 0.f, a2 = 0.f, a3 = 0.f;
        float a4 = 0.f, a5 = 0.f, a6 = 0.f, a7 = 0.f;
#pragma unroll
        for (int j = 0; j < 64; j += 8) {
            a0 = fmaf(XXr[j + 0], lane_bcast(z, j + 0), a0);
            a1 = fmaf(XXr[j + 1], lane_bcast(z, j + 1), a1);
            a2 = fmaf(XXr[j + 2], lane_bcast(z, j + 2), a2);
            a3 = fmaf(XXr[j + 3], lane_bcast(z, j + 3), a3);
            a4 = fmaf(XXr[j + 4], lane_bcast(z, j + 4), a4);
            a5 = fmaf(XXr[j + 5], lane_bcast(z, j + 5), a5);
            a6 = fmaf(XXr[j + 6], lane_bcast(z, j + 6), a6);
            a7 = fmaf(XXr[j + 7], lane_bcast(z, j + 7), a7);
        }
        float dot = ((a0 + a1) + (a2 + a3)) + ((a4 + a5) + (a6 + a7));
        float Gall = 0.5f * (dot - XYr);

        float E = lane_bcast(Gall, 63);          // lane 63 of matvec is E
        float Gv = m_own ? Gall : 0.f;           // masked gradient vector

        // c-sums: lane-local products (no shuffle needed), DPP reductions
        float c0 = wave_sum64(k1u * Gv);
        float c1 = wave_sum64(k1v * Gv);
        float c2 = wave_sum64(k1d * Gv);

        // 4 parallel bpermutes for the stencil rows of G
        float Gp  = __shfl(Gv, t + 21);   // G[t+21] (valid if mu)
        float Gm  = __shfl(Gv, t - 21);   // G[t-21] (valid if t>=21)
        float Gpp = __shfl(Gv, t + 42);   // G[t+42] (valid if mpp)
        float Gmm = __shfl(Gv, t - 42);   // G[t-42] (valid if mmm)
        float Gp_m  = mu  ? Gp  : 0.f;
        float Gm_m  = (t >= 21) ? Gm : 0.f;
        float Gpp_m = mpp ? Gpp : 0.f;
        float Gmm_m = mmm ? Gmm : 0.f;

        // gradient stencils for the three k1 replicas
        float gk1v = k20 * Gm_m  + k21 * Gv  + k22 * Gp_m;   // at index t
        float gk1u = k20 * Gv    + k21 * Gp_m + k22 * Gpp_m; // at index t+21
        float gk1d = k20 * Gmm_m + k21 * Gm_m + k22 * Gv;    // at index t-21

        // updates (all from pre-update values; scalar ones uniform per lane)
        float bE = b1 * E;
        k1v -= m_own ? LRf * gk1v : 0.f;
        k1u -= mu    ? LRf * gk1u : 0.f;
        k1d -= md    ? LRf * gk1d : 0.f;
        k20 -= LRf * (bE + c0);
        k21 -= LRf * (bE + c1);
        k22 -= LRf * (bE + c2);
        b1  -= LRf * (S * E);
        b2  -= LRf * E;
    }

    // emit final effective kernel
    float A = k20 * k1u + k21 * k1v + k22 * k1d;
    AF[t] = m_own ? A : (b2 + b1 * (k20 + k21 + k22));
}

// ---------------- apply: out = y - yhat(final params) ----------------
__global__ __launch_bounds__(256) void k_apply(const float* __restrict__ in,
                                               const float* __restrict__ AF,
                                               float* __restrict__ out) {
    __shared__ float xs[3][276];
    __shared__ float As[64];
    const int n = blockIdx.x, t = threadIdx.x;
    float* xsf = &xs[0][0];
    for (int p = t; p < 3 * 276; p += 256) xsf[p] = 0.f;
    if (t < 64) As[t] = AF[t];
    __syncthreads();
    for (int p = t; p < 3 * 256; p += 256) {
        int r = p >> 8, w = p & 255;
        xs[r][10 + w] = in[(n * 4 + 1 + r) * 256 + w];
    }
    __syncthreads();
    float s = As[63];  // beff
#pragma unroll
    for (int r = 0; r < 3; ++r)
#pragma unroll
        for (int a = 0; a < 21; ++a)
            s += As[r * 21 + a] * xs[r][t + a];
    out[n * 256 + t] = in[(n * 4) * 256 + t] - s;
}

extern "C" void kernel_launch(void* const* d_in, const int* in_sizes, int n_in,
                              void* d_out, int out_size, void* d_ws, size_t ws_size,
                              hipStream_t stream) {
    const float* in = (const float*)d_in[0];
    const float* k1 = (const float*)d_in[1];
    const float* b1 = (const float*)d_in[2];
    const float* k2 = (const float*)d_in[3];
    const float* b2 = (const float*)d_in[4];
    float* out = (float*)d_out;
    float* ws = (float*)d_ws;

    const size_t need = (size_t)(AF_OFF + 64) * sizeof(float);  // ~4.02 MiB
    if (ws_size >= need) {
        float* P = ws;
        float* ST = ws + ST_OFF;
        float* AF = ws + AF_OFF;
        k_stats<0><<<NBLK, 256, 0, stream>>>(in, P);
        k_reduce<<<16, 256, 0, stream>>>(P, ST);
        k_train<<<1, 64, 0, stream>>>(ST, k1, b1, k2, b2, AF);
        k_apply<<<1024, 256, 0, stream>>>(in, AF, out);
    } else {
        float* ST = ws;
        float* AF = ws + PSTRIDE;
        hipMemsetAsync(ST, 0, PSTRIDE * sizeof(float), stream);
        k_stats<1><<<NBLK, 256, 0, stream>>>(in, ST);
        k_train<<<1, 64, 0, stream>>>(ST, k1, b1, k2, b2, AF);
        k_apply<<<1024, 256, 0, stream>>>(in, AF, out);
    }
}

// Round 5
// 308.322 us; speedup vs baseline: 1.0178x; 1.0178x over previous
//
#include <hip/hip_runtime.h>

// Problem: 500 GD steps on a 2-conv model, loss = ||FFT(y)-FFT(yhat)||^2.
// Parseval => loss = 256 * sum (y - yhat)^2 ; mean over batch 1024 => 2c = 0.5.
// yhat[n,w] = beff + sum_{i=(r,a)} A[i] * xpad[n, r, w+a-10],
//   A[r,a] = sum_h k2[h]*k1[r-h+1,a],  beff = b2 + b1*(k2[0]+k2[1]+k2[2]).
// Sufficient stats: XX[63][63], XY[63], Sx[63], Ysum. Train on those; then apply.
//
// k_train R5: the R3/R4 rocprof evidence (VGPR_Count pinned at 68,
// FETCH_SIZE ~13.5MB/dispatch vs a 16KB input) showed the XXr[64] ALLOCA was
// never promoted to registers -- it lived in scratch, and scratch reloads
// (HBM-latency) dominated every iteration. asm pins on array elements only
// pinned scratch round-trips. Fix: replace the array with 64 macro-generated
// NAMED SCALARS (pure SSA, no alloca), keep __launch_bounds__(64,1) +
// amdgpu_waves_per_eu(1) for the VGPR budget, and pin the SSA values so the
// loads cannot be rematerialized inside the 500-iteration loop.

#define NB1 4              // batch rows per k_stats block
#define NBLK 256           // 1024 / NB1
#define PSTRIDE 4096       // 3969 XX + 63 XY + 63 Sx + 1 Ysum = 4096
#define ST_OFF (NBLK * PSTRIDE)     // 1048576 floats
#define AF_OFF (ST_OFF + PSTRIDE)   // 1052672 floats

// ---------------- stats kernel ----------------
template <int ATOMIC>
__global__ __launch_bounds__(256) void k_stats(const float* __restrict__ in,
                                               float* __restrict__ Pbase) {
    __shared__ float xs[NB1][3][276];   // zero-padded rows: u+10, u in [-10,265]
    __shared__ float ys[NB1][256];
    const int tid = threadIdx.x;
    const int n0 = blockIdx.x * NB1;

    float* xsf = &xs[0][0][0];
    for (int p = tid; p < NB1 * 3 * 276; p += 256) xsf[p] = 0.f;
    __syncthreads();
    for (int p = tid; p < NB1 * 4 * 256; p += 256) {
        int w = p & 255, h = (p >> 8) & 3, n = p >> 10;
        float v = in[((n0 + n) * 4 + h) * 256 + w];
        if (h == 0) ys[n][w] = v;
        else xs[n][h - 1][10 + w] = v;
    }
    __syncthreads();

    // rows: i = 4*ti + p (broadcast across the 16 lanes of a row);
    // cols: j = 16*q + tj  -> lanes read CONSECUTIVE words (bank-conflict-free)
    const int ti = tid >> 4, tj = tid & 15;
    const int i0 = ti * 4;
    int ir[4], ia[4], jr[4], ja[4];
#pragma unroll
    for (int p = 0; p < 4; ++p) {
        int i = i0 + p; if (i > 62) i = 62;
        ir[p] = i / 21; ia[p] = i % 21;
        int j = p * 16 + tj; if (j > 62) j = 62;
        jr[p] = j / 21; ja[p] = j % 21;
    }
    float acc[4][4] = {{0.f, 0.f, 0.f, 0.f}, {0.f, 0.f, 0.f, 0.f},
                       {0.f, 0.f, 0.f, 0.f}, {0.f, 0.f, 0.f, 0.f}};
    for (int n = 0; n < NB1; ++n) {
        const float* ba0 = &xs[n][ir[0]][ia[0]];
        const float* ba1 = &xs[n][ir[1]][ia[1]];
        const float* ba2 = &xs[n][ir[2]][ia[2]];
        const float* ba3 = &xs[n][ir[3]][ia[3]];
        const float* bb0 = &xs[n][jr[0]][ja[0]];
        const float* bb1 = &xs[n][jr[1]][ja[1]];
        const float* bb2 = &xs[n][jr[2]][ja[2]];
        const float* bb3 = &xs[n][jr[3]][ja[3]];
#pragma unroll 4
        for (int w = 0; w < 256; ++w) {
            float va0 = ba0[w], va1 = ba1[w], va2 = ba2[w], va3 = ba3[w];
            float vb0 = bb0[w], vb1 = bb1[w], vb2 = bb2[w], vb3 = bb3[w];
            acc[0][0] += va0 * vb0; acc[0][1] += va0 * vb1;
            acc[0][2] += va0 * vb2; acc[0][3] += va0 * vb3;
            acc[1][0] += va1 * vb0; acc[1][1] += va1 * vb1;
            acc[1][2] += va1 * vb2; acc[1][3] += va1 * vb3;
            acc[2][0] += va2 * vb0; acc[2][1] += va2 * vb1;
            acc[2][2] += va2 * vb2; acc[2][3] += va2 * vb3;
            acc[3][0] += va3 * vb0; acc[3][1] += va3 * vb1;
            acc[3][2] += va3 * vb2; acc[3][3] += va3 * vb3;
        }
    }
    float* Pb = ATOMIC ? Pbase : (Pbase + blockIdx.x * PSTRIDE);
#pragma unroll
    for (int p = 0; p < 4; ++p)
#pragma unroll
        for (int q = 0; q < 4; ++q) {
            int i = i0 + p, j = q * 16 + tj;   // raw (unclamped) indices
            if (i < 63 && j < 63) {
                if (ATOMIC) unsafeAtomicAdd(&Pb[i * 63 + j], acc[p][q]);
                else Pb[i * 63 + j] = acc[p][q];
            }
        }
    if (tid < 127) {
        float a2 = 0.f;
        int slot;
        if (tid < 63) {
            int r = tid / 21, a = tid % 21;
            for (int n = 0; n < NB1; ++n) {
                const float* xa = &xs[n][r][a];
                const float* yy = ys[n];
                float s = 0.f;
                for (int w = 0; w < 256; ++w) s += xa[w] * yy[w];
                a2 += s;
            }
            slot = 3969 + tid;
        } else if (tid < 126) {
            int e = tid - 63, r = e / 21, a = e % 21;
            for (int n = 0; n < NB1; ++n) {
                const float* xa = &xs[n][r][a];
                float s = 0.f;
                for (int w = 0; w < 256; ++w) s += xa[w];
                a2 += s;
            }
            slot = 4032 + e;
        } else {
            for (int n = 0; n < NB1; ++n) {
                const float* yy = ys[n];
                float s = 0.f;
                for (int w = 0; w < 256; ++w) s += yy[w];
                a2 += s;
            }
            slot = 4095;
        }
        if (ATOMIC) unsafeAtomicAdd(&Pb[slot], a2);
        else Pb[slot] = a2;
    }
}

// ---------------- deterministic reduction over block partials ----------------
__global__ __launch_bounds__(256) void k_reduce(const float* __restrict__ P,
                                                float* __restrict__ ST) {
    int e = blockIdx.x * 256 + threadIdx.x;  // 0..4095, coalesced over b-iters
    double s = 0.0;
    for (int b = 0; b < NBLK; ++b) s += (double)P[b * PSTRIDE + e];
    ST[e] = (float)s;
}

// ---------------- DPP helpers (VALU-pipe cross-lane) ----------------
template <int CTRL>
__device__ __forceinline__ float dpp_sum_step(float v) {
    int moved = __builtin_amdgcn_update_dpp(0, __float_as_int(v), CTRL, 0xf, 0xf, false);
    return v + __int_as_float(moved);
}
// full-wave (64) sum; returns total as a wave-uniform value (via lane 63)
__device__ __forceinline__ float wave_sum64(float v) {
    v = dpp_sum_step<0x111>(v);   // row_shr:1
    v = dpp_sum_step<0x112>(v);   // row_shr:2
    v = dpp_sum_step<0x114>(v);   // row_shr:4
    v = dpp_sum_step<0x118>(v);   // row_shr:8
    v = dpp_sum_step<0x142>(v);   // row_bcast:15
    v = dpp_sum_step<0x143>(v);   // row_bcast:31
    return __int_as_float(__builtin_amdgcn_readlane(__float_as_int(v), 63));
}
__device__ __forceinline__ float lane_bcast(float v, int lane) {
    return __int_as_float(__builtin_amdgcn_readlane(__float_as_int(v), lane));
}

// 64 named scalars for the augmented matrix row -- NO alloca, pure SSA.
#define FOR63(X) \
  X(0) X(1) X(2) X(3) X(4) X(5) X(6) X(7) X(8) X(9) \
  X(10) X(11) X(12) X(13) X(14) X(15) X(16) X(17) X(18) X(19) \
  X(20) X(21) X(22) X(23) X(24) X(25) X(26) X(27) X(28) X(29) \
  X(30) X(31) X(32) X(33) X(34) X(35) X(36) X(37) X(38) X(39) \
  X(40) X(41) X(42) X(43) X(44) X(45) X(46) X(47) X(48) X(49) \
  X(50) X(51) X(52) X(53) X(54) X(55) X(56) X(57) X(58) X(59) \
  X(60) X(61) X(62)
#define DECLM(j) float m##j;
#define LOADM(j) m##j = rowp[j];
#define PINM(j)  asm volatile("" : "+v"(m##j));
#define MV(j, a) a = fmaf(m##j, lane_bcast(z, j), a);
#define MV8(J0,J1,J2,J3,J4,J5,J6,J7) \
  MV(J0, a0) MV(J1, a1) MV(J2, a2) MV(J3, a3) \
  MV(J4, a4) MV(J5, a5) MV(J6, a6) MV(J7, a7)

// ---------------- training: 500 GD steps, one wave, register-resident ------
__global__ __launch_bounds__(64, 1)
__attribute__((amdgpu_waves_per_eu(1)))
void k_train(const float* __restrict__ ST,
             const float* __restrict__ k1_in,
             const float* __restrict__ b1_in,
             const float* __restrict__ k2_in,
             const float* __restrict__ b2_in,
             float* __restrict__ AF) {
    const int t = threadIdx.x;

    // Augmented row M[t][:]: t<63 -> [XX[t,:], Sx[t]]; t==63 -> [Sx[:], NW].
    FOR63(DECLM) float m63;
    const float* rowp = (t < 63) ? (ST + t * 63) : (ST + 4032);
    FOR63(LOADM)
    m63 = (t < 63) ? ST[4032 + t] : 262144.f;   // Sx[t] | NW
    float XYr = (t < 63) ? ST[3969 + t] : ST[4095];    // XY[t] | Ysum

    // Pin the SSA values into VGPRs once, before the loop: the asm output is
    // opaque, so the loads above cannot be sunk/rematerialized per-iteration.
    FOR63(PINM)
    asm volatile("" : "+v"(m63));
    asm volatile("" : "+v"(XYr));

    // validity masks for the replicated/shifted k1 state
    const bool m_own = (t < 63);             // lane owns k1[t]
    const bool mu    = (t < 42);             // k1[t+21] exists
    const bool md    = (t >= 21 && t < 63);  // k1[t-21] exists (lane63 excluded)
    const bool mpp   = (t < 21);             // G[t+42] valid row for k1u update
    const bool mmm   = (t >= 42);            // G[t-42] valid row for k1d update

    // replicated state: k1v = k1[t], k1u = k1[t+21], k1d = k1[t-21] (masked 0)
    float k1v = m_own ? k1_in[t] : 0.f;
    float k1u = mu ? k1_in[t + 21] : 0.f;
    float k1d = md ? k1_in[t - 21] : 0.f;
    // scalars replicated in every lane (identical updates -> identical values)
    float k20 = k2_in[0], k21 = k2_in[1], k22 = k2_in[2];
    float b1 = b1_in[0], b2 = b2_in[0];

    const float LRf = 1e-7f;

    for (int it = 0; it < 500; ++it) {
        float S = k20 + k21 + k22;
        float beff = b2 + b1 * S;
        // A[t] = k20*k1[t+21] + k21*k1[t] + k22*k1[t-21]  (pure per-lane FMA)
        float A = k20 * k1u + k21 * k1v + k22 * k1d;
        float z = m_own ? A : beff;   // A==0 at lane 63

        // G_all = 0.5*(M.z - rhs) via readlane-broadcast matvec (no LDS)
        float a0 = 0.f, a1 = 0.f, a2 = 0.f, a3 = 0.f;
        float a4 = 0.f, a5 = 0.f, a6 = 0.f, a7 = 0.f;
        MV8( 0,  1,  2,  3,  4,  5,  6,  7)
        MV8( 8,  9, 10, 11, 12, 13, 14, 15)
        MV8(16, 17, 18, 19, 20, 21, 22, 23)
        MV8(24, 25, 26, 27, 28, 29, 30, 31)
        MV8(32, 33, 34, 35, 36, 37, 38, 39)
        MV8(40, 41, 42, 43, 44, 45, 46, 47)
        MV8(48, 49, 50, 51, 52, 53, 54, 55)
        MV8(56, 57, 58, 59, 60, 61, 62, 63)
        float dot = ((a0 + a1) + (a2 + a3)) + ((a4 + a5) + (a6 + a7));
        float Gall = 0.5f * (dot - XYr);

        float E = lane_bcast(Gall, 63);          // lane 63 of matvec is E
        float Gv = m_own ? Gall : 0.f;           // masked gradient vector

        // c-sums: lane-local products (no shuffle needed), DPP reductions
        float c0 = wave_sum64(k1u * Gv);
        float c1 = wave_sum64(k1v * Gv);
        float c2 = wave_sum64(k1d * Gv);

        // 4 parallel bpermutes for the stencil rows of G
        float Gp  = __shfl(Gv, t + 21);   // G[t+21] (valid if mu)
        float Gm  = __shfl(Gv, t - 21);   // G[t-21] (valid if t>=21)
        float Gpp = __shfl(Gv, t + 42);   // G[t+42] (valid if mpp)
        float Gmm = __shfl(Gv, t - 42);   // G[t-42] (valid if mmm)
        float Gp_m  = mu  ? Gp  : 0.f;
        float Gm_m  = (t >= 21) ? Gm : 0.f;
        float Gpp_m = mpp ? Gpp : 0.f;
        float Gmm_m = mmm ? Gmm : 0.f;

        // gradient stencils for the three k1 replicas
        float gk1v = k20 * Gm_m  + k21 * Gv  + k22 * Gp_m;   // at index t
        float gk1u = k20 * Gv    + k21 * Gp_m + k22 * Gpp_m; // at index t+21
        float gk1d = k20 * Gmm_m + k21 * Gm_m + k22 * Gv;    // at index t-21

        // updates (all from pre-update values; scalar ones uniform per lane)
        float bE = b1 * E;
        k1v -= m_own ? LRf * gk1v : 0.f;
        k1u -= mu    ? LRf * gk1u : 0.f;
        k1d -= md    ? LRf * gk1d : 0.f;
        k20 -= LRf * (bE + c0);
        k21 -= LRf * (bE + c1);
        k22 -= LRf * (bE + c2);
        b1  -= LRf * (S * E);
        b2  -= LRf * E;
    }

    // emit final effective kernel
    float A = k20 * k1u + k21 * k1v + k22 * k1d;
    AF[t] = m_own ? A : (b2 + b1 * (k20 + k21 + k22));
}

// ---------------- apply: out = y - yhat(final params) ----------------
__global__ __launch_bounds__(256) void k_apply(const float* __restrict__ in,
                                               const float* __restrict__ AF,
                                               float* __restrict__ out) {
    __shared__ float xs[3][276];
    __shared__ float As[64];
    const int n = blockIdx.x, t = threadIdx.x;
    float* xsf = &xs[0][0];
    for (int p = t; p < 3 * 276; p += 256) xsf[p] = 0.f;
    if (t < 64) As[t] = AF[t];
    __syncthreads();
    for (int p = t; p < 3 * 256; p += 256) {
        int r = p >> 8, w = p & 255;
        xs[r][10 + w] = in[(n * 4 + 1 + r) * 256 + w];
    }
    __syncthreads();
    float s = As[63];  // beff
#pragma unroll
    for (int r = 0; r < 3; ++r)
#pragma unroll
        for (int a = 0; a < 21; ++a)
            s += As[r * 21 + a] * xs[r][t + a];
    out[n * 256 + t] = in[(n * 4) * 256 + t] - s;
}

extern "C" void kernel_launch(void* const* d_in, const int* in_sizes, int n_in,
                              void* d_out, int out_size, void* d_ws, size_t ws_size,
                              hipStream_t stream) {
    const float* in = (const float*)d_in[0];
    const float* k1 = (const float*)d_in[1];
    const float* b1 = (const float*)d_in[2];
    const float* k2 = (const float*)d_in[3];
    const float* b2 = (const float*)d_in[4];
    float* out = (float*)d_out;
    float* ws = (float*)d_ws;

    const size_t need = (size_t)(AF_OFF + 64) * sizeof(float);  // ~4.02 MiB
    if (ws_size >= need) {
        float* P = ws;
        float* ST = ws + ST_OFF;
        float* AF = ws + AF_OFF;
        k_stats<0><<<NBLK, 256, 0, stream>>>(in, P);
        k_reduce<<<16, 256, 0, stream>>>(P, ST);
        k_train<<<1, 64, 0, stream>>>(ST, k1, b1, k2, b2, AF);
        k_apply<<<1024, 256, 0, stream>>>(in, AF, out);
    } else {
        float* ST = ws;
        float* AF = ws + PSTRIDE;
        hipMemsetAsync(ST, 0, PSTRIDE * sizeof(float), stream);
        k_stats<1><<<NBLK, 256, 0, stream>>>(in, ST);
        k_train<<<1, 64, 0, stream>>>(ST, k1, b1, k2, b2, AF);
        k_apply<<<1024, 256, 0, stream>>>(in, AF, out);
    }
}